// Round 8
// baseline (171.847 us; speedup 1.0000x reference)
//
#include <hip/hip_runtime.h>

// Fuzzy decoder: num[p,s,o] = max_k min(t0[s,k], t_p[k,o]); out = t + num - t*num.
// S=K=O=512, p in {0,1}. Packed-fp16 semiring GEMM (v_pk_min/v_pk_max), fp32 epilogue.
// R8: pay global latency ONCE per chunk with loads in flight UNDER compute, never
// right before a barrier (compiler emits s_waitcnt vmcnt(0) before s_barrier — R7's
// per-chunk prefetch-then-barrier serialized full HBM latency 4x under the harness's
// 268MB poison-drain congestion). NCH=2, BK=256, 34KB single-buffer LDS, grid 512.

#define SDIM 512
#define TS 32      // s-tile per block
#define TO 32      // o-tile per block
#define BK 256     // k per chunk
#define NKQ 64     // k-quads (4 k) per chunk
#define NCH 2      // chunks
#define RSTR 34    // padded row stride in uint2 (272 B, 16B-aligned)

typedef _Float16 h2 __attribute__((ext_vector_type(2)));

__device__ __forceinline__ h2 pack2(float a, float b) {
    return __builtin_bit_cast(h2, __builtin_amdgcn_cvt_pkrtz(a, b));  // v_cvt_pkrtz_f16_f32
}
__device__ __forceinline__ h2 pmin(h2 a, h2 b) { return __builtin_elementwise_min(a, b); }
__device__ __forceinline__ h2 pmax(h2 a, h2 b) { return __builtin_elementwise_max(a, b); }
__device__ __forceinline__ h2 bch2(unsigned u) { return __builtin_bit_cast(h2, u); }
__device__ __forceinline__ unsigned b32(h2 v) { return __builtin_bit_cast(unsigned, v); }

__global__ __launch_bounds__(256, 2) void fuzzy_compose_kernel(
        const float* __restrict__ t, float* __restrict__ out) {
    // A2[kq][s] = uint2{ h2(k=4kq,4kq+1), h2(4kq+2,4kq+3) } for s-row s  (kq within chunk)
    __shared__ uint2 A2[NKQ][RSTR];
    __shared__ uint2 B2[NKQ][RSTR];

    const int tid = threadIdx.x;
    const int o0 = blockIdx.x * TO;   // 16 o-tiles
    const int s0 = blockIdx.y * TS;   // 16 s-tiles
    const int p  = blockIdx.z;        // 2 predicates
    const float* __restrict__ Bmat = t + p * (SDIM * SDIM);

    // compute mapping: 2 s-rows x 2 o-cols per thread
    const int ol = (tid & 15) * 2;
    const int sl = (tid >> 4) * 2;

    // A staging: row ar (0..31), f4-phase aq (0..7): kq = aq + 8q, q=0..7
    const int ar = tid >> 3, aq = tid & 7;
    // B staging: kq = g*32 + bkq (g=0..1), 4 rows each, f4-col bq
    const int bkq = tid >> 3, bq = tid & 7;

    const float4* __restrict__ Arow =
        reinterpret_cast<const float4*>(t + (s0 + ar) * SDIM);

    h2 acc[2][2][2];
    #pragma unroll
    for (int j = 0; j < 2; ++j)
        #pragma unroll
        for (int i = 0; i < 2; ++i) {
            acc[j][i][0] = pack2(0.f, 0.f);
            acc[j][i][1] = pack2(0.f, 0.f);
        }

    float4 fa[8], fb[2][4];
    // prologue: load chunk 0 (16 b128, max MLP — the only exposed drain)
    #pragma unroll
    for (int q = 0; q < 8; ++q) fa[q] = Arow[aq + 8 * q];
    #pragma unroll
    for (int g = 0; g < 2; ++g)
        #pragma unroll
        for (int r = 0; r < 4; ++r)
            fb[g][r] = *reinterpret_cast<const float4*>(
                Bmat + ((g * 32 + bkq) * 4 + r) * SDIM + o0 + bq * 4);

    for (int c = 0; c < NCH; ++c) {
        // ---- stage chunk c (regs -> LDS) ----
        #pragma unroll
        for (int q = 0; q < 8; ++q) {
            const int f = aq + 8 * q;     // kq within chunk
            uint2 u;
            u.x = b32(pack2(fa[q].x, fa[q].y));
            u.y = b32(pack2(fa[q].z, fa[q].w));
            A2[f][ar] = u;
        }
        #pragma unroll
        for (int g = 0; g < 2; ++g) {
            const int kq = g * 32 + bkq;
            uint4 u01, u23;
            u01.x = b32(pack2(fb[g][0].x, fb[g][1].x)); u01.y = b32(pack2(fb[g][2].x, fb[g][3].x));
            u01.z = b32(pack2(fb[g][0].y, fb[g][1].y)); u01.w = b32(pack2(fb[g][2].y, fb[g][3].y));
            u23.x = b32(pack2(fb[g][0].z, fb[g][1].z)); u23.y = b32(pack2(fb[g][2].z, fb[g][3].z));
            u23.z = b32(pack2(fb[g][0].w, fb[g][1].w)); u23.w = b32(pack2(fb[g][2].w, fb[g][3].w));
            *reinterpret_cast<uint4*>(&B2[kq][bq * 4 + 0]) = u01;
            *reinterpret_cast<uint4*>(&B2[kq][bq * 4 + 2]) = u23;
        }
        __syncthreads();   // tile visible

        // issue chunk c+1 global loads NOW: ~5us of compute below hides them
        if (c + 1 < NCH) {
            const int kf4 = (c + 1) * (BK / 4);
            #pragma unroll
            for (int q = 0; q < 8; ++q) fa[q] = Arow[kf4 + aq + 8 * q];
            #pragma unroll
            for (int g = 0; g < 2; ++g)
                #pragma unroll
                for (int r = 0; r < 4; ++r)
                    fb[g][r] = *reinterpret_cast<const float4*>(
                        Bmat + ((c + 1) * BK + (g * 32 + bkq) * 4 + r) * SDIM + o0 + bq * 4);
        }

        // ---- compute: per kq = 1 b128 (A) + 1 b128 (B) + 16 pk; offsets immediate ----
        #pragma unroll
        for (int kq = 0; kq < NKQ; ++kq) {
            const uint4 ua = *reinterpret_cast<const uint4*>(&A2[kq][sl]);
            const uint4 ub = *reinterpret_cast<const uint4*>(&B2[kq][ol]);
            const h2 a0e = bch2(ua.x), a0o = bch2(ua.y);
            const h2 a1e = bch2(ua.z), a1o = bch2(ua.w);
            const h2 b0e = bch2(ub.x), b0o = bch2(ub.y);
            const h2 b1e = bch2(ub.z), b1o = bch2(ub.w);
            acc[0][0][0] = pmax(acc[0][0][0], pmin(a0e, b0e));
            acc[0][0][1] = pmax(acc[0][0][1], pmin(a0o, b0o));
            acc[0][1][0] = pmax(acc[0][1][0], pmin(a0e, b1e));
            acc[0][1][1] = pmax(acc[0][1][1], pmin(a0o, b1o));
            acc[1][0][0] = pmax(acc[1][0][0], pmin(a1e, b0e));
            acc[1][0][1] = pmax(acc[1][0][1], pmin(a1o, b0o));
            acc[1][1][0] = pmax(acc[1][1][0], pmin(a1e, b1e));
            acc[1][1][1] = pmax(acc[1][1][1], pmin(a1o, b1o));
        }

        if (c + 1 < NCH) __syncthreads();   // readers done before next stage overwrites
    }

    // fused epilogue: num = max over 4 fp16 partial maxes; out = t + num - t*num (fp32)
    const float* __restrict__ tp = t + p * (SDIM * SDIM);
    float* __restrict__ op = out + p * (SDIM * SDIM);
    #pragma unroll
    for (int j = 0; j < 2; ++j) {
        const int row = s0 + sl + j;
        const float2 tv = *reinterpret_cast<const float2*>(tp + row * SDIM + o0 + ol);
        const h2 m0 = pmax(acc[j][0][0], acc[j][0][1]);
        const h2 m1 = pmax(acc[j][1][0], acc[j][1][1]);
        const float n0 = fmaxf((float)m0[0], (float)m0[1]);
        const float n1 = fmaxf((float)m1[0], (float)m1[1]);
        float2 r;
        r.x = tv.x + n0 - tv.x * n0;
        r.y = tv.y + n1 - tv.y * n1;
        *reinterpret_cast<float2*>(op + row * SDIM + o0 + ol) = r;
    }
}

extern "C" void kernel_launch(void* const* d_in, const int* in_sizes, int n_in,
                              void* d_out, int out_size, void* d_ws, size_t ws_size,
                              hipStream_t stream) {
    const float* t = (const float*)d_in[0];
    float* out = (float*)d_out;
    dim3 grid(SDIM / TO, SDIM / TS, 2);   // 16 x 16 x 2 = 512 blocks (2/CU)
    fuzzy_compose_kernel<<<grid, 256, 0, stream>>>(t, out);
}

// Round 9
// 102.673 us; speedup vs baseline: 1.6737x; 1.6737x over previous
//
#include <hip/hip_runtime.h>

// Fuzzy decoder: num[p,s,o] = max_k min(t0[s,k], t_p[k,o]); out = t + num - t*num.
// S=K=O=512, p in {0,1}. Packed-fp16 semiring GEMM (v_pk_min/v_pk_max), fp32 epilogue.
// R9: R7's k-quad uint2 layout (1 A-b128 + 1 B-b128 per 2 k2) + BK=128 (32 staged
// VGPRs only -- R8's 64 spilled: SGPR 112 + 350MB phantom scratch traffic) +
// double-buffered LDS, ONE barrier/chunk (4 total), ordered
// [issue loads c+1 | compute c | stage c+1 | barrier] so the barrier's vmcnt(0)
// drain is already satisfied (R7's prefetch-before-barrier exposed HBM latency 4x).

#define SDIM 512
#define TS 32      // s-tile per block
#define TO 32      // o-tile per block
#define BK 128     // k per chunk
#define NKQ 32     // k-quads (4 k) per chunk
#define NCH 4      // chunks
#define RSTR 34    // padded row stride in uint2 (272 B, 16B-aligned)

typedef _Float16 h2 __attribute__((ext_vector_type(2)));

__device__ __forceinline__ h2 pack2(float a, float b) {
    return __builtin_bit_cast(h2, __builtin_amdgcn_cvt_pkrtz(a, b));  // v_cvt_pkrtz_f16_f32
}
__device__ __forceinline__ h2 pmin(h2 a, h2 b) { return __builtin_elementwise_min(a, b); }
__device__ __forceinline__ h2 pmax(h2 a, h2 b) { return __builtin_elementwise_max(a, b); }
__device__ __forceinline__ h2 bch2(unsigned u) { return __builtin_bit_cast(h2, u); }
__device__ __forceinline__ unsigned b32(h2 v) { return __builtin_bit_cast(unsigned, v); }

__global__ __launch_bounds__(256, 2) void fuzzy_compose_kernel(
        const float* __restrict__ t, float* __restrict__ out) {
    // A2[buf][kq][s] = uint2{ h2(k=4kq,4kq+1), h2(4kq+2,4kq+3) } for s-row s
    __shared__ uint2 A2[2][NKQ][RSTR];
    __shared__ uint2 B2[2][NKQ][RSTR];

    const int tid = threadIdx.x;
    const int o0 = blockIdx.x * TO;   // 16 o-tiles
    const int s0 = blockIdx.y * TS;   // 16 s-tiles
    const int p  = blockIdx.z;        // 2 predicates
    const float* __restrict__ Bmat = t + p * (SDIM * SDIM);

    // compute mapping: 2 s-rows x 2 o-cols per thread
    const int ol = (tid & 15) * 2;
    const int sl = (tid >> 4) * 2;

    // A staging: row ar (0..31), f4-phase aq (0..7): kq = aq + 8q, q=0..3
    const int ar = tid >> 3, aq = tid & 7;
    // B staging: k-quad bkq (0..31) = 4 consecutive k-rows, f4-col bq (0..7)
    const int bkq = tid >> 3, bq = tid & 7;

    const float4* __restrict__ Arow =
        reinterpret_cast<const float4*>(t + (s0 + ar) * SDIM);

    h2 acc[2][2][2];
    #pragma unroll
    for (int j = 0; j < 2; ++j)
        #pragma unroll
        for (int i = 0; i < 2; ++i) {
            acc[j][i][0] = pack2(0.f, 0.f);
            acc[j][i][1] = pack2(0.f, 0.f);
        }

    float4 fa[4], fb[4];

    // ---- prologue: load chunk 0, stage into buf0, barrier (no vmem in flight) ----
    #pragma unroll
    for (int q = 0; q < 4; ++q) fa[q] = Arow[aq + 8 * q];
    #pragma unroll
    for (int r = 0; r < 4; ++r)
        fb[r] = *reinterpret_cast<const float4*>(Bmat + (4 * bkq + r) * SDIM + o0 + bq * 4);

    #pragma unroll
    for (int q = 0; q < 4; ++q) {
        const int f = aq + 8 * q;
        uint2 u;
        u.x = b32(pack2(fa[q].x, fa[q].y));
        u.y = b32(pack2(fa[q].z, fa[q].w));
        A2[0][f][ar] = u;
    }
    {
        uint4 u01, u23;
        u01.x = b32(pack2(fb[0].x, fb[1].x)); u01.y = b32(pack2(fb[2].x, fb[3].x));
        u01.z = b32(pack2(fb[0].y, fb[1].y)); u01.w = b32(pack2(fb[2].y, fb[3].y));
        u23.x = b32(pack2(fb[0].z, fb[1].z)); u23.y = b32(pack2(fb[2].z, fb[3].z));
        u23.z = b32(pack2(fb[0].w, fb[1].w)); u23.w = b32(pack2(fb[2].w, fb[3].w));
        *reinterpret_cast<uint4*>(&B2[0][bkq][bq * 4 + 0]) = u01;
        *reinterpret_cast<uint4*>(&B2[0][bkq][bq * 4 + 2]) = u23;
    }
    __syncthreads();   // buf0 ready; vmcnt already drained by the stores above

    for (int c = 0; c < NCH; ++c) {
        // issue chunk c+1 global loads: latency hides under the compute below
        if (c + 1 < NCH) {
            const int kf4 = (c + 1) * (BK / 4);
            #pragma unroll
            for (int q = 0; q < 4; ++q) fa[q] = Arow[kf4 + aq + 8 * q];
            #pragma unroll
            for (int r = 0; r < 4; ++r)
                fb[r] = *reinterpret_cast<const float4*>(
                    Bmat + ((c + 1) * BK + 4 * bkq + r) * SDIM + o0 + bq * 4);
        }

        // ---- compute chunk c: per kq = 1 b128 (A) + 1 b128 (B) + 16 pk ----
        const int buf = c & 1;
        #pragma unroll
        for (int kq = 0; kq < NKQ; ++kq) {
            const uint4 ua = *reinterpret_cast<const uint4*>(&A2[buf][kq][sl]);
            const uint4 ub = *reinterpret_cast<const uint4*>(&B2[buf][kq][ol]);
            const h2 a0e = bch2(ua.x), a0o = bch2(ua.y);
            const h2 a1e = bch2(ua.z), a1o = bch2(ua.w);
            const h2 b0e = bch2(ub.x), b0o = bch2(ub.y);
            const h2 b1e = bch2(ub.z), b1o = bch2(ub.w);
            acc[0][0][0] = pmax(acc[0][0][0], pmin(a0e, b0e));
            acc[0][0][1] = pmax(acc[0][0][1], pmin(a0o, b0o));
            acc[0][1][0] = pmax(acc[0][1][0], pmin(a0e, b1e));
            acc[0][1][1] = pmax(acc[0][1][1], pmin(a0o, b1o));
            acc[1][0][0] = pmax(acc[1][0][0], pmin(a1e, b0e));
            acc[1][0][1] = pmax(acc[1][0][1], pmin(a1o, b0o));
            acc[1][1][0] = pmax(acc[1][1][0], pmin(a1e, b1e));
            acc[1][1][1] = pmax(acc[1][1][1], pmin(a1o, b1o));
        }

        // ---- stage chunk c+1 into the other buffer, then the chunk barrier ----
        if (c + 1 < NCH) {
            const int nb = (c + 1) & 1;
            #pragma unroll
            for (int q = 0; q < 4; ++q) {
                const int f = aq + 8 * q;
                uint2 u;
                u.x = b32(pack2(fa[q].x, fa[q].y));
                u.y = b32(pack2(fa[q].z, fa[q].w));
                A2[nb][f][ar] = u;
            }
            uint4 u01, u23;
            u01.x = b32(pack2(fb[0].x, fb[1].x)); u01.y = b32(pack2(fb[2].x, fb[3].x));
            u01.z = b32(pack2(fb[0].y, fb[1].y)); u01.w = b32(pack2(fb[2].y, fb[3].y));
            u23.x = b32(pack2(fb[0].z, fb[1].z)); u23.y = b32(pack2(fb[2].z, fb[3].z));
            u23.z = b32(pack2(fb[0].w, fb[1].w)); u23.w = b32(pack2(fb[2].w, fb[3].w));
            *reinterpret_cast<uint4*>(&B2[nb][bkq][bq * 4 + 0]) = u01;
            *reinterpret_cast<uint4*>(&B2[nb][bkq][bq * 4 + 2]) = u23;
            __syncthreads();   // buf[nb] ready; everyone done reading buf[c&1]
        }
    }

    // fused epilogue: num = max over 4 fp16 partial maxes; out = t + num - t*num (fp32)
    const float* __restrict__ tp = t + p * (SDIM * SDIM);
    float* __restrict__ op = out + p * (SDIM * SDIM);
    #pragma unroll
    for (int j = 0; j < 2; ++j) {
        const int row = s0 + sl + j;
        const float2 tv = *reinterpret_cast<const float2*>(tp + row * SDIM + o0 + ol);
        const h2 m0 = pmax(acc[j][0][0], acc[j][0][1]);
        const h2 m1 = pmax(acc[j][1][0], acc[j][1][1]);
        const float n0 = fmaxf((float)m0[0], (float)m0[1]);
        const float n1 = fmaxf((float)m1[0], (float)m1[1]);
        float2 r;
        r.x = tv.x + n0 - tv.x * n0;
        r.y = tv.y + n1 - tv.y * n1;
        *reinterpret_cast<float2*>(op + row * SDIM + o0 + ol) = r;
    }
}

extern "C" void kernel_launch(void* const* d_in, const int* in_sizes, int n_in,
                              void* d_out, int out_size, void* d_ws, size_t ws_size,
                              hipStream_t stream) {
    const float* t = (const float*)d_in[0];
    float* out = (float*)d_out;
    dim3 grid(SDIM / TO, SDIM / TS, 2);   // 16 x 16 x 2 = 512 blocks (2/CU)
    fuzzy_compose_kernel<<<grid, 256, 0, stream>>>(t, out);
}

// Round 10
// 83.507 us; speedup vs baseline: 2.0579x; 1.2295x over previous
//
#include <hip/hip_runtime.h>

// Fuzzy decoder: num[p,s,o] = max_k min(t0[s,k], t_p[k,o]); out = t + num - t*num.
// S=K=O=512, p in {0,1}. R10: A-operand in SGPRs (wave-uniform scalar loads, zero LDS
// cost), B transposed in LDS read as ds_read_b128, each B element reused across 4
// s-rows in registers. Plain fp32 v_min/v_max (exact). Lane = 4s x 1o.
// LDS floor ~10us (vs ~20us for all previous 2sx2o structures), VALU ~7us.

#define SDIM 512
#define BK 64      // k per chunk
#define NCH 8      // chunks
#define BKP 68     // padded k-stride of Bt row: start-bank = 4*(o+m) -> uniform, no hot bank

__global__ __launch_bounds__(256, 2) void fuzzy_compose_kernel(
        const float* __restrict__ t, float* __restrict__ out) {
    __shared__ float Bt[64][BKP];   // Bt[o_local][kk] = B[c*64+kk][o0+o_local]

    const int tid = threadIdx.x;
    const int o0 = blockIdx.x * 64;   // 8 o-strips
    const int s0 = blockIdx.y * 16;   // 32 s-blocks
    const int p  = blockIdx.z;        // 2 predicates
    const float* __restrict__ Bm = t + p * (SDIM * SDIM);

    const int lane = tid & 63;
    // wave id, forced wave-uniform so A-row addresses scalarize to s_load
    const int wv = __builtin_amdgcn_readfirstlane(tid >> 6);   // 0..3
    const int srow = s0 + wv * 4;
    const float* __restrict__ A0 = t + (srow + 0) * SDIM;
    const float* __restrict__ A1 = t + (srow + 1) * SDIM;
    const float* __restrict__ A2 = t + (srow + 2) * SDIM;
    const float* __restrict__ A3 = t + (srow + 3) * SDIM;

    // staging map: thread loads k-rows 4kq..4kq+3 at o-quad 4oq (4x float4), transposes
    const int kq = tid >> 4;   // 0..15
    const int oq = tid & 15;   // 0..15

    float fbuf[4][4];
    #pragma unroll
    for (int r = 0; r < 4; ++r)
        *reinterpret_cast<float4*>(&fbuf[r][0]) =
            *reinterpret_cast<const float4*>(Bm + (4 * kq + r) * SDIM + o0 + 4 * oq);

    float acc0 = 0.f, acc1 = 0.f, acc2 = 0.f, acc3 = 0.f;

    for (int c = 0; c < NCH; ++c) {
        // ---- stage chunk c: 4x4 register transpose -> 4 ds_write_b128 ----
        #pragma unroll
        for (int j = 0; j < 4; ++j) {
            float4 ty;
            ty.x = fbuf[0][j]; ty.y = fbuf[1][j]; ty.z = fbuf[2][j]; ty.w = fbuf[3][j];
            *reinterpret_cast<float4*>(&Bt[4 * oq + j][4 * kq]) = ty;
        }
        __syncthreads();

        // issue chunk c+1 global loads (hidden under compute; tail barrier drains them)
        if (c + 1 < NCH) {
            #pragma unroll
            for (int r = 0; r < 4; ++r)
                *reinterpret_cast<float4*>(&fbuf[r][0]) =
                    *reinterpret_cast<const float4*>(
                        Bm + ((c + 1) * BK + 4 * kq + r) * SDIM + o0 + 4 * oq);
        }

        // ---- compute: per 4k = 1 ds_read_b128 (B) + 32 v_min/v_max, A from SGPRs ----
        const float* __restrict__ a0 = A0 + c * BK;
        const float* __restrict__ a1 = A1 + c * BK;
        const float* __restrict__ a2 = A2 + c * BK;
        const float* __restrict__ a3 = A3 + c * BK;
        #pragma unroll
        for (int m = 0; m < 16; ++m) {
            const float4 b = *reinterpret_cast<const float4*>(&Bt[lane][4 * m]);
            const float bb[4] = {b.x, b.y, b.z, b.w};
            #pragma unroll
            for (int i = 0; i < 4; ++i) {
                const int kk = 4 * m + i;
                acc0 = fmaxf(acc0, fminf(a0[kk], bb[i]));
                acc1 = fmaxf(acc1, fminf(a1[kk], bb[i]));
                acc2 = fmaxf(acc2, fminf(a2[kk], bb[i]));
                acc3 = fmaxf(acc3, fminf(a3[kk], bb[i]));
            }
        }
        __syncthreads();
    }

    // fused epilogue: out = t + num - t*num (exact fp32), coalesced b32 per row
    const float* __restrict__ tpp = t + p * (SDIM * SDIM);
    float* __restrict__ op = out + p * (SDIM * SDIM);
    {
        const int col = o0 + lane;
        float tv;
        tv = tpp[(srow + 0) * SDIM + col];
        op[(srow + 0) * SDIM + col] = tv + acc0 - tv * acc0;
        tv = tpp[(srow + 1) * SDIM + col];
        op[(srow + 1) * SDIM + col] = tv + acc1 - tv * acc1;
        tv = tpp[(srow + 2) * SDIM + col];
        op[(srow + 2) * SDIM + col] = tv + acc2 - tv * acc2;
        tv = tpp[(srow + 3) * SDIM + col];
        op[(srow + 3) * SDIM + col] = tv + acc3 - tv * acc3;
    }
}

extern "C" void kernel_launch(void* const* d_in, const int* in_sizes, int n_in,
                              void* d_out, int out_size, void* d_ws, size_t ws_size,
                              hipStream_t stream) {
    const float* t = (const float*)d_in[0];
    float* out = (float*)d_out;
    dim3 grid(8, 32, 2);   // o-strips x s-blocks x p = 512 blocks (2/CU)
    fuzzy_compose_kernel<<<grid, 256, 0, stream>>>(t, out);
}